// Round 5
// baseline (1700.295 us; speedup 1.0000x reference)
//
#include <hip/hip_runtime.h>

// RealNVP forward, fused across all 8 coupling layers.  Round 5.
// B=131072, D=64, H=256, L=8. out = y[B*D] ++ logdet[B], fp32.
//
// R4 -> R5: kill the residual scratch spill by SHRINKING the per-wave register
// working set instead of raising the cap. Evidence: R4 still moved 0.86 GB of
// excess HBM traffic at bounds(256,3); reported VGPR 84 = exactly half of the
// 168 budget (and R3: 64 = 128/2) -> allocator splits unified file ~50/50
// arch/AGPR and the 84 arch side spills (~100 B/thread/net-iter ~= 0.85 GB).
// New shape: 512 threads, 8 waves = 4(m-quarters of hidden) x 2(n-halves of
// batch). Per-wave: acc[4][2]=32 AGPR (+8 acc3), afr[4]+bfr[2]=24 arch frags,
// state yv[2][4]+s3h[2]+lda[2]=14 arch. Need ~70 arch + 40 AGPR = ~110 <= 128
// budget at __launch_bounds__(512,4) -> 2 blocks/CU (16 waves/CU, up from 12).
// LDS unchanged 40960 B -> 81920 B for 2 blocks <= 160 KiB. MFMA count, layout,
// barrier structure identical to R4.

#define BATCH    131072
#define DIM      64
#define HID      256
#define NLAYER   8
#define BM       64
#define NTHREADS 512

typedef _Float16 f16;
typedef __attribute__((ext_vector_type(8))) _Float16 f16x8;
typedef __attribute__((ext_vector_type(4))) _Float16 f16x4;
typedef __attribute__((ext_vector_type(4))) float    f32x4;

#define TWO_LOG2E 2.8853900817779268f   // 2*log2(e)
#define LOG2E     1.4426950408889634f

__device__ __forceinline__ float tanh_fast(float x) {
  // tanh(x) = 1 - 2/(e^{2x}+1); exact +-1 limits at inf -> no clamps needed.
  float e = __builtin_amdgcn_exp2f(x * TWO_LOG2E);
  return 1.f - 2.f * __builtin_amdgcn_rcpf(e + 1.f);
}

// Swizzled LDS element offsets. Row stride act=512B (256 h), xm=128B (64 k).
// 16B chunk index XORed with row&7 -> b128 column reads across 16 rows hit 8
// distinct chunks twice each (2-way bank alias = free, m136). b64 preserved.
__device__ __forceinline__ int act_idx(int row, int h) {
  int b = h << 1;
  return (row * 512 + (((b & ~15) ^ ((row & 7) << 4)) | (b & 15))) >> 1;
}
__device__ __forceinline__ int xm_idx(int row, int k) {
  int b = k << 1;
  return (row * 128 + (((b & ~15) ^ ((row & 7) << 4)) | (b & 15))) >> 1;
}

// fp32 -> fp16 weight pack, all 6 tensors in one launch.
__global__ void cvt6_kernel(const float* s0, f16* d0, const float* s1, f16* d1,
                            const float* s2, f16* d2, const float* s3, f16* d3,
                            const float* s4, f16* d4, const float* s5, f16* d5) {
  // quad counts: 32768, 131072, 32768, 32768, 131072, 32768 (total 393216)
  int i = blockIdx.x * blockDim.x + threadIdx.x;
  const float* s; f16* d; int base;
  if      (i < 32768)  { s = s0; d = d0; base = 0; }
  else if (i < 163840) { s = s1; d = d1; base = 32768; }
  else if (i < 196608) { s = s2; d = d2; base = 163840; }
  else if (i < 229376) { s = s3; d = d3; base = 196608; }
  else if (i < 360448) { s = s4; d = d4; base = 229376; }
  else                 { s = s5; d = d5; base = 360448; }
  int k = i - base;
  float4 v = ((const float4*)s)[k];
  f16x4 o;
  o[0] = (f16)v.x; o[1] = (f16)v.y; o[2] = (f16)v.z; o[3] = (f16)v.w;
  ((f16x4*)d)[k] = o;
}

__global__ __launch_bounds__(NTHREADS, 4) void flow_kernel(
    const float* __restrict__ x, const float* __restrict__ masks,
    const f16* __restrict__ wS1, const f16* __restrict__ wS2, const f16* __restrict__ wS3,
    const float* __restrict__ sb1, const float* __restrict__ sb2, const float* __restrict__ sb3,
    const float* __restrict__ scl,
    const f16* __restrict__ wT1, const f16* __restrict__ wT2, const f16* __restrict__ wT3,
    const float* __restrict__ tb1, const float* __restrict__ tb2, const float* __restrict__ tb3,
    float* __restrict__ y_out, float* __restrict__ ld_out)
{
  __shared__ __attribute__((aligned(16))) f16 act [BM * 256];  // 32768 B, swizzled
  __shared__ __attribute__((aligned(16))) f16 xm_s[BM * 64];   //  8192 B, swizzled
  float* ld_red = (float*)xm_s;  // aliased: xm dead by the time logdet reduces

  const int tid  = threadIdx.x;
  const int lane = tid & 63;
  const int wv   = tid >> 6;        // wave 0..7
  const int wn   = wv & 1;          // batch half (n-tiles 2x16)
  const int wm   = wv >> 1;         // hidden quarter (mm1/mm2), D quarter (mm3)
  const int quad = lane >> 4;
  const int l16  = lane & 15;
  const int row0 = blockIdx.x * BM;
  const int d0   = wm * 16 + quad * 4;   // this lane's D base (mm3 C-tile)
  const int bn0  = wn * 32 + l16;        // batch row base (+n*16)

  // Per-lane state: batch row = bn0 + n*16, D = d0+r  (mm3 C-layout).
  float yv[2][4];    // flow state, fp32
  f16x4 s3h[2];      // s output of scale net (f16 to save VGPRs)
  float lda[2];      // logdet accumulator per n
  #pragma unroll
  for (int n = 0; n < 2; ++n) {
    const float4 v = *(const float4*)&x[(size_t)(row0 + bn0 + n * 16) * DIM + d0];
    yv[n][0] = v.x; yv[n][1] = v.y; yv[n][2] = v.z; yv[n][3] = v.w;
    lda[n] = 0.f;
  }

  const f32x4 fzero = {0.f, 0.f, 0.f, 0.f};

  #pragma unroll 1
  for (int l = 0; l < NLAYER; ++l) {
    const float4 mv = *(const float4*)&masks[l * DIM + d0];   // mask for D=d0..d0+3

    // xm = y*mask -> LDS (B-operand of mm1), one b64 per n
    #pragma unroll
    for (int n = 0; n < 2; ++n) {
      f16x4 o;
      o[0] = (f16)(yv[n][0] * mv.x); o[1] = (f16)(yv[n][1] * mv.y);
      o[2] = (f16)(yv[n][2] * mv.z); o[3] = (f16)(yv[n][3] * mv.w);
      *(f16x4*)&xm_s[xm_idx(bn0 + n * 16, d0)] = o;
    }
    __syncthreads();                                     // (1) xm ready

    #pragma unroll 1
    for (int net = 0; net < 2; ++net) {
      const f16*   W1 = (net ? wT1 : wS1) + l * HID * DIM;
      const f16*   W2 = (net ? wT2 : wS2) + l * HID * HID;
      const f16*   W3 = (net ? wT3 : wS3) + l * DIM * HID;
      const float* b1 = (net ? tb1 : sb1) + l * HID;
      const float* b2 = (net ? tb2 : sb2) + l * HID;
      const float* b3 = (net ? tb3 : sb3) + l * DIM;

      f32x4 acc[4][2];   // [m = hidden 16-tile][n = batch 16-tile]
      #pragma unroll
      for (int m = 0; m < 4; ++m)
        #pragma unroll
        for (int n = 0; n < 2; ++n) acc[m][n] = fzero;

      // ---- mm1 (transposed): C[h, b] = W1 @ xm^T ----
      #pragma unroll
      for (int kt = 0; kt < 2; ++kt) {
        const int k0 = kt * 32 + quad * 8;
        f16x8 afr[4], bfr[2];
        #pragma unroll
        for (int m = 0; m < 4; ++m)
          afr[m] = *(const f16x8*)&W1[(wm * 64 + m * 16 + l16) * DIM + k0];
        #pragma unroll
        for (int n = 0; n < 2; ++n)
          bfr[n] = *(const f16x8*)&xm_s[xm_idx(bn0 + n * 16, k0)];
        #pragma unroll
        for (int m = 0; m < 4; ++m)
          #pragma unroll
          for (int n = 0; n < 2; ++n)
            acc[m][n] = __builtin_amdgcn_mfma_f32_16x16x32_f16(afr[m], bfr[n], acc[m][n], 0, 0, 0);
      }
      // ep1: act[b, h..h+3] = tanh(. + b1)  -- contiguous b64 per (m,n)
      #pragma unroll
      for (int m = 0; m < 4; ++m) {
        const int   h0  = wm * 64 + m * 16 + quad * 4;
        const float4 bv = *(const float4*)&b1[h0];
        #pragma unroll
        for (int n = 0; n < 2; ++n) {
          f16x4 o;
          o[0] = (f16)tanh_fast(acc[m][n][0] + bv.x);
          o[1] = (f16)tanh_fast(acc[m][n][1] + bv.y);
          o[2] = (f16)tanh_fast(acc[m][n][2] + bv.z);
          o[3] = (f16)tanh_fast(acc[m][n][3] + bv.w);
          *(f16x4*)&act[act_idx(bn0 + n * 16, h0)] = o;
        }
      }
      __syncthreads();                                   // (2) h1 ready

      // ---- mm2 (transposed): W2 @ h1^T, residual tanh ----
      #pragma unroll
      for (int m = 0; m < 4; ++m)
        #pragma unroll
        for (int n = 0; n < 2; ++n) acc[m][n] = fzero;
      #pragma unroll
      for (int kt = 0; kt < 8; ++kt) {
        const int k0 = kt * 32 + quad * 8;
        f16x8 afr[4], bfr[2];
        #pragma unroll
        for (int m = 0; m < 4; ++m)
          afr[m] = *(const f16x8*)&W2[(wm * 64 + m * 16 + l16) * HID + k0];
        #pragma unroll
        for (int n = 0; n < 2; ++n)
          bfr[n] = *(const f16x8*)&act[act_idx(bn0 + n * 16, k0)];
        #pragma unroll
        for (int m = 0; m < 4; ++m)
          #pragma unroll
          for (int n = 0; n < 2; ++n)
            acc[m][n] = __builtin_amdgcn_mfma_f32_16x16x32_f16(afr[m], bfr[n], acc[m][n], 0, 0, 0);
      }
      __syncthreads();                                   // (3) all done reading act
      #pragma unroll
      for (int m = 0; m < 4; ++m) {
        const int   h0  = wm * 64 + m * 16 + quad * 4;
        const float4 bv = *(const float4*)&b2[h0];
        #pragma unroll
        for (int n = 0; n < 2; ++n) {
          f16x4* p = (f16x4*)&act[act_idx(bn0 + n * 16, h0)];
          const f16x4 prev = *p;                         // own cell (same lane wrote it)
          f16x4 o;
          o[0] = (f16)tanh_fast(acc[m][n][0] + bv.x + (float)prev[0]);
          o[1] = (f16)tanh_fast(acc[m][n][1] + bv.y + (float)prev[1]);
          o[2] = (f16)tanh_fast(acc[m][n][2] + bv.z + (float)prev[2]);
          o[3] = (f16)tanh_fast(acc[m][n][3] + bv.w + (float)prev[3]);
          *p = o;
        }
      }
      __syncthreads();                                   // (4) h2 ready

      // ---- mm3 (transposed): W3 @ h2^T -> C[D, b] ----
      f32x4 acc3[2];
      #pragma unroll
      for (int n = 0; n < 2; ++n) acc3[n] = fzero;
      #pragma unroll
      for (int kt = 0; kt < 8; ++kt) {
        const int k0  = kt * 32 + quad * 8;
        const f16x8 a3 = *(const f16x8*)&W3[(wm * 16 + l16) * HID + k0];
        #pragma unroll
        for (int n = 0; n < 2; ++n) {
          const f16x8 bfr = *(const f16x8*)&act[act_idx(bn0 + n * 16, k0)];
          acc3[n] = __builtin_amdgcn_mfma_f32_16x16x32_f16(a3, bfr, acc3[n], 0, 0, 0);
        }
      }
      if (net == 0) __syncthreads();   // (5) act free for net1's ep1
      // net1's post-mm3 overwrite of act is guarded by next layer's barrier (1)

      const float4 b3v = *(const float4*)&b3[d0];
      if (net == 0) {
        const float4 sv = *(const float4*)&scl[l * DIM + d0];
        #pragma unroll
        for (int n = 0; n < 2; ++n) {
          s3h[n][0] = (f16)((tanh_fast(acc3[n][0] + b3v.x) + yv[n][0] * mv.x) * sv.x);
          s3h[n][1] = (f16)((tanh_fast(acc3[n][1] + b3v.y) + yv[n][1] * mv.y) * sv.y);
          s3h[n][2] = (f16)((tanh_fast(acc3[n][2] + b3v.z) + yv[n][2] * mv.z) * sv.z);
          s3h[n][3] = (f16)((tanh_fast(acc3[n][3] + b3v.w) + yv[n][3] * mv.w) * sv.w);
        }
      } else {
        const float om[4] = {1.f - mv.x, 1.f - mv.y, 1.f - mv.z, 1.f - mv.w};
        const float mm4[4] = {mv.x, mv.y, mv.z, mv.w};
        #pragma unroll
        for (int n = 0; n < 2; ++n) {
          #pragma unroll
          for (int r = 0; r < 4; ++r) {
            const float y0 = yv[n][r];
            const float s  = (float)s3h[n][r];
            const float tv = acc3[n][r] + ((const float*)&b3v)[r] + y0 * mm4[r];
            const float e  = __builtin_amdgcn_exp2f(s * LOG2E);
            yv[n][r] = mm4[r] * y0 + om[r] * (y0 * e + tv);
            lda[n]  += om[r] * s;
          }
        }
      }
    } // net
  } // layers

  // y out: coalesced dwordx4 per n
  #pragma unroll
  for (int n = 0; n < 2; ++n) {
    float4 v; v.x = yv[n][0]; v.y = yv[n][1]; v.z = yv[n][2]; v.w = yv[n][3];
    *(float4*)&y_out[(size_t)(row0 + bn0 + n * 16) * DIM + d0] = v;
  }

  // logdet: lda[n] = this lane's partial over D=d0..d0+3 for batch row bn0+n*16.
  // Reduce over quad (shfl xor 16/32 within wave), then over the 4 wm-waves
  // via LDS (aliased on xm_s; all xm reads are behind barriers (2)-(4)).
  float v0 = lda[0], v1 = lda[1];
  v0 += __shfl_xor(v0, 16); v0 += __shfl_xor(v0, 32);
  v1 += __shfl_xor(v1, 16); v1 += __shfl_xor(v1, 32);
  __syncthreads();                   // xm region now safe to reuse
  if (quad == 0) {
    ld_red[(bn0 +  0) * 4 + wm] = v0;
    ld_red[(bn0 + 16) * 4 + wm] = v1;
  }
  __syncthreads();
  if (tid < BM)
    ld_out[row0 + tid] = ld_red[tid * 4 + 0] + ld_red[tid * 4 + 1]
                       + ld_red[tid * 4 + 2] + ld_red[tid * 4 + 3];
}

extern "C" void kernel_launch(void* const* d_in, const int* in_sizes, int n_in,
                              void* d_out, int out_size, void* d_ws, size_t ws_size,
                              hipStream_t stream) {
  const float* x     = (const float*)d_in[0];
  const float* masks = (const float*)d_in[1];
  const float* sW1f  = (const float*)d_in[2];
  const float* sb1   = (const float*)d_in[3];
  const float* sW2f  = (const float*)d_in[4];
  const float* sb2   = (const float*)d_in[5];
  const float* sW3f  = (const float*)d_in[6];
  const float* sb3   = (const float*)d_in[7];
  const float* scl   = (const float*)d_in[8];
  const float* tW1f  = (const float*)d_in[9];
  const float* tb1   = (const float*)d_in[10];
  const float* tW2f  = (const float*)d_in[11];
  const float* tb2   = (const float*)d_in[12];
  const float* tW3f  = (const float*)d_in[13];
  const float* tb3   = (const float*)d_in[14];
  (void)in_sizes; (void)n_in; (void)out_size; (void)ws_size;

  const int W1SZ = NLAYER * HID * DIM;   // 131072
  const int W2SZ = NLAYER * HID * HID;   // 524288
  const int W3SZ = NLAYER * DIM * HID;   // 131072
  f16* wS1 = (f16*)d_ws;
  f16* wS2 = wS1 + W1SZ;
  f16* wS3 = wS2 + W2SZ;
  f16* wT1 = wS3 + W3SZ;
  f16* wT2 = wT1 + W1SZ;
  f16* wT3 = wT2 + W2SZ;

  // total float4 quads = 393216 -> 1536 blocks x 256
  cvt6_kernel<<<1536, 256, 0, stream>>>(sW1f, wS1, sW2f, wS2, sW3f, wS3,
                                        tW1f, wT1, tW2f, wT2, tW3f, wT3);

  float* y_out  = (float*)d_out;
  float* ld_out = y_out + (size_t)BATCH * DIM;
  flow_kernel<<<BATCH / BM, NTHREADS, 0, stream>>>(
      x, masks, wS1, wS2, wS3, sb1, sb2, sb3, scl,
      wT1, wT2, wT3, tb1, tb2, tb3, y_out, ld_out);
}

// Round 7
// 993.988 us; speedup vs baseline: 1.7106x; 1.7106x over previous
//
#include <hip/hip_runtime.h>

// RealNVP forward, fused across all 8 coupling layers.  Round 7 (= R6 + compile fix).
// B=131072, D=64, H=256, L=8. out = y[B*D] ++ logdet[B], fp32.
//
// Register model consolidated over R3-R5: unified VGPR budget = 2048*4/CU /
// waves_per_CU; rocprof VGPR_Count reports the arch half. Demand was ~170 vs
// R4's 168 budget -> persistent scratch spill (R4: 0.86 GB excess HBM traffic).
// This round = R4 structure (256 thr, bounds(256,3), transposed matmuls, XOR
// swizzle) minus ~12 arch registers:
//  - s3 state: 8 VGPRs -> LDS f16 [64][68] (8.7 KB; same-lane write->read so
//    no new barriers; +4 pad makes the b64 access 2-way-bank-alias = free).
//  - all f32->f16 conversions via v_cvt_pkrtz_f16_f32 (packed, 2 elems/inst):
//    fewer live temps + ~45 us VALU saved across 1.07e9 conversions.
//    (fix vs R6: builtin returns __fp16x2 -> bit_cast to _Float16x2.)
//  - fragment loads restructured per-n (1 bfr live instead of 4).
// LDS 32768 + 8192 + 8704 = 49664 B -> still 3 blocks/CU (148992 <= 163840).

#define BATCH    131072
#define DIM      64
#define HID      256
#define NLAYER   8
#define BM       64
#define NTHREADS 256

typedef _Float16 f16;
typedef __attribute__((ext_vector_type(8))) _Float16 f16x8;
typedef __attribute__((ext_vector_type(4))) _Float16 f16x4;
typedef __attribute__((ext_vector_type(2))) _Float16 f16x2;
typedef __attribute__((ext_vector_type(2))) __fp16   hf16x2;   // builtin's return type
typedef __attribute__((ext_vector_type(4))) float    f32x4;

#define TWO_LOG2E 2.8853900817779268f   // 2*log2(e)
#define LOG2E     1.4426950408889634f

__device__ __forceinline__ float tanh_fast(float x) {
  // tanh(x) = 1 - 2/(e^{2x}+1); exact +-1 limits at inf -> no clamps needed.
  float e = __builtin_amdgcn_exp2f(x * TWO_LOG2E);
  return 1.f - 2.f * __builtin_amdgcn_rcpf(e + 1.f);
}

// Pack 4 f32 -> f16x4 with two v_cvt_pkrtz_f16_f32.
__device__ __forceinline__ f16x4 pk4(float a, float b, float c, float d) {
  f16x2 lo = __builtin_bit_cast(f16x2, __builtin_amdgcn_cvt_pkrtz(a, b));
  f16x2 hi = __builtin_bit_cast(f16x2, __builtin_amdgcn_cvt_pkrtz(c, d));
  f16x4 o; o[0] = lo[0]; o[1] = lo[1]; o[2] = hi[0]; o[3] = hi[1];
  return o;
}

// Swizzled LDS element offsets. Row stride act=512B (256 h), xm=128B (64 k).
// 16B chunk index XORed with row&7 -> b128 column reads across 16 rows hit 8
// distinct chunks twice each (2-way bank alias = free, m136). b64 preserved.
__device__ __forceinline__ int act_idx(int row, int h) {
  int b = h << 1;
  return (row * 512 + (((b & ~15) ^ ((row & 7) << 4)) | (b & 15))) >> 1;
}
__device__ __forceinline__ int xm_idx(int row, int k) {
  int b = k << 1;
  return (row * 128 + (((b & ~15) ^ ((row & 7) << 4)) | (b & 15))) >> 1;
}

// fp32 -> fp16 weight pack, all 6 tensors in one launch.
__global__ void cvt6_kernel(const float* s0, f16* d0, const float* s1, f16* d1,
                            const float* s2, f16* d2, const float* s3, f16* d3,
                            const float* s4, f16* d4, const float* s5, f16* d5) {
  // quad counts: 32768, 131072, 32768, 32768, 131072, 32768 (total 393216)
  int i = blockIdx.x * blockDim.x + threadIdx.x;
  const float* s; f16* d; int base;
  if      (i < 32768)  { s = s0; d = d0; base = 0; }
  else if (i < 163840) { s = s1; d = d1; base = 32768; }
  else if (i < 196608) { s = s2; d = d2; base = 163840; }
  else if (i < 229376) { s = s3; d = d3; base = 196608; }
  else if (i < 360448) { s = s4; d = d4; base = 229376; }
  else                 { s = s5; d = d5; base = 360448; }
  int k = i - base;
  float4 v = ((const float4*)s)[k];
  ((f16x4*)d)[k] = pk4(v.x, v.y, v.z, v.w);
}

__global__ __launch_bounds__(NTHREADS, 3) void flow_kernel(
    const float* __restrict__ x, const float* __restrict__ masks,
    const f16* __restrict__ wS1, const f16* __restrict__ wS2, const f16* __restrict__ wS3,
    const float* __restrict__ sb1, const float* __restrict__ sb2, const float* __restrict__ sb3,
    const float* __restrict__ scl,
    const f16* __restrict__ wT1, const f16* __restrict__ wT2, const f16* __restrict__ wT3,
    const float* __restrict__ tb1, const float* __restrict__ tb2, const float* __restrict__ tb3,
    float* __restrict__ y_out, float* __restrict__ ld_out)
{
  __shared__ __attribute__((aligned(16))) f16 act [BM * 256];      // 32768 B, swizzled
  __shared__ __attribute__((aligned(16))) f16 xm_s[BM * 64];       //  8192 B, swizzled
  __shared__ __attribute__((aligned(16))) f16 s3_s[BM * (DIM+4)];  //  8704 B, padded
  float* ld_red = (float*)xm_s;  // aliased: xm dead by the time logdet reduces

  const int tid  = threadIdx.x;
  const int lane = tid & 63;
  const int wv   = tid >> 6;        // wave 0..3: hidden-quarter (mm1/mm2), D-quarter (mm3)
  const int quad = lane >> 4;
  const int l16  = lane & 15;
  const int row0 = blockIdx.x * BM;
  const int d0   = wv * 16 + quad * 4;   // this lane's D base (4 consecutive)

  // Per-lane state: batch row = n*16+l16, D = d0+r  (mm3 C-layout).
  float yv[4][4];    // flow state, fp32
  float lda[4];      // logdet accumulator per n
  #pragma unroll
  for (int n = 0; n < 4; ++n) {
    const float4 v = *(const float4*)&x[(size_t)(row0 + n * 16 + l16) * DIM + d0];
    yv[n][0] = v.x; yv[n][1] = v.y; yv[n][2] = v.z; yv[n][3] = v.w;
    lda[n] = 0.f;
  }

  const f32x4 fzero = {0.f, 0.f, 0.f, 0.f};

  #pragma unroll 1
  for (int l = 0; l < NLAYER; ++l) {
    const float4 mv = *(const float4*)&masks[l * DIM + d0];   // mask for D=d0..d0+3

    // xm = y*mask -> LDS (B-operand of mm1), one b64 per n
    #pragma unroll
    for (int n = 0; n < 4; ++n)
      *(f16x4*)&xm_s[xm_idx(n * 16 + l16, d0)] =
          pk4(yv[n][0] * mv.x, yv[n][1] * mv.y, yv[n][2] * mv.z, yv[n][3] * mv.w);
    __syncthreads();                                     // (1) xm ready

    #pragma unroll 1
    for (int net = 0; net < 2; ++net) {
      const f16*   W1 = (net ? wT1 : wS1) + l * HID * DIM;
      const f16*   W2 = (net ? wT2 : wS2) + l * HID * HID;
      const f16*   W3 = (net ? wT3 : wS3) + l * DIM * HID;
      const float* b1 = (net ? tb1 : sb1) + l * HID;
      const float* b2 = (net ? tb2 : sb2) + l * HID;
      const float* b3 = (net ? tb3 : sb3) + l * DIM;

      f32x4 acc[4][4];   // [m = hidden tile][n = batch tile]
      #pragma unroll
      for (int m = 0; m < 4; ++m)
        #pragma unroll
        for (int n = 0; n < 4; ++n) acc[m][n] = fzero;

      // ---- mm1 (transposed): C[h, b] = W1 @ xm^T ----
      #pragma unroll
      for (int kt = 0; kt < 2; ++kt) {
        const int k0 = kt * 32 + quad * 8;
        f16x8 afr[4];
        #pragma unroll
        for (int m = 0; m < 4; ++m)
          afr[m] = *(const f16x8*)&W1[(wv * 64 + m * 16 + l16) * DIM + k0];
        #pragma unroll
        for (int n = 0; n < 4; ++n) {
          const f16x8 bfr = *(const f16x8*)&xm_s[xm_idx(n * 16 + l16, k0)];
          #pragma unroll
          for (int m = 0; m < 4; ++m)
            acc[m][n] = __builtin_amdgcn_mfma_f32_16x16x32_f16(afr[m], bfr, acc[m][n], 0, 0, 0);
        }
      }
      // ep1: act[b, h..h+3] = tanh(. + b1)  -- contiguous b64 per (m,n)
      #pragma unroll
      for (int m = 0; m < 4; ++m) {
        const int   h0  = wv * 64 + m * 16 + quad * 4;
        const float4 bv = *(const float4*)&b1[h0];
        #pragma unroll
        for (int n = 0; n < 4; ++n)
          *(f16x4*)&act[act_idx(n * 16 + l16, h0)] =
              pk4(tanh_fast(acc[m][n][0] + bv.x), tanh_fast(acc[m][n][1] + bv.y),
                  tanh_fast(acc[m][n][2] + bv.z), tanh_fast(acc[m][n][3] + bv.w));
      }
      __syncthreads();                                   // (2) h1 ready

      // ---- mm2 (transposed): W2 @ h1^T, residual tanh ----
      #pragma unroll
      for (int m = 0; m < 4; ++m)
        #pragma unroll
        for (int n = 0; n < 4; ++n) acc[m][n] = fzero;
      #pragma unroll 2
      for (int kt = 0; kt < 8; ++kt) {
        const int k0 = kt * 32 + quad * 8;
        f16x8 afr[4];
        #pragma unroll
        for (int m = 0; m < 4; ++m)
          afr[m] = *(const f16x8*)&W2[(wv * 64 + m * 16 + l16) * HID + k0];
        #pragma unroll
        for (int n = 0; n < 4; ++n) {
          const f16x8 bfr = *(const f16x8*)&act[act_idx(n * 16 + l16, k0)];
          #pragma unroll
          for (int m = 0; m < 4; ++m)
            acc[m][n] = __builtin_amdgcn_mfma_f32_16x16x32_f16(afr[m], bfr, acc[m][n], 0, 0, 0);
        }
      }
      __syncthreads();                                   // (3) all done reading act
      #pragma unroll
      for (int m = 0; m < 4; ++m) {
        const int   h0  = wv * 64 + m * 16 + quad * 4;
        const float4 bv = *(const float4*)&b2[h0];
        #pragma unroll
        for (int n = 0; n < 4; ++n) {
          f16x4* p = (f16x4*)&act[act_idx(n * 16 + l16, h0)];
          const f16x4 prev = *p;                         // own cell (same lane wrote it)
          *p = pk4(tanh_fast(acc[m][n][0] + bv.x + (float)prev[0]),
                   tanh_fast(acc[m][n][1] + bv.y + (float)prev[1]),
                   tanh_fast(acc[m][n][2] + bv.z + (float)prev[2]),
                   tanh_fast(acc[m][n][3] + bv.w + (float)prev[3]));
        }
      }
      __syncthreads();                                   // (4) h2 ready

      // ---- mm3 (transposed): W3 @ h2^T -> C[D, b] ----
      f32x4 acc3[4];
      #pragma unroll
      for (int n = 0; n < 4; ++n) acc3[n] = fzero;
      #pragma unroll 2
      for (int kt = 0; kt < 8; ++kt) {
        const int k0  = kt * 32 + quad * 8;
        const f16x8 a3 = *(const f16x8*)&W3[(wv * 16 + l16) * HID + k0];
        #pragma unroll
        for (int n = 0; n < 4; ++n) {
          const f16x8 bfr = *(const f16x8*)&act[act_idx(n * 16 + l16, k0)];
          acc3[n] = __builtin_amdgcn_mfma_f32_16x16x32_f16(a3, bfr, acc3[n], 0, 0, 0);
        }
      }
      if (net == 0) __syncthreads();   // (5) act free for net1's ep1
      // net1's post-mm3 overwrite of act is guarded by next layer's barrier (1)

      const float4 b3v = *(const float4*)&b3[d0];
      if (net == 0) {
        const float4 sv = *(const float4*)&scl[l * DIM + d0];
        // s3 -> LDS (same lane reads it back in net1's epilogue; no barrier
        // needed for same-lane LDS RAW).
        #pragma unroll
        for (int n = 0; n < 4; ++n)
          *(f16x4*)&s3_s[(n * 16 + l16) * (DIM + 4) + d0] =
              pk4((tanh_fast(acc3[n][0] + b3v.x) + yv[n][0] * mv.x) * sv.x,
                  (tanh_fast(acc3[n][1] + b3v.y) + yv[n][1] * mv.y) * sv.y,
                  (tanh_fast(acc3[n][2] + b3v.z) + yv[n][2] * mv.z) * sv.z,
                  (tanh_fast(acc3[n][3] + b3v.w) + yv[n][3] * mv.w) * sv.w);
      } else {
        const float om[4] = {1.f - mv.x, 1.f - mv.y, 1.f - mv.z, 1.f - mv.w};
        const float mm4[4] = {mv.x, mv.y, mv.z, mv.w};
        #pragma unroll
        for (int n = 0; n < 4; ++n) {
          const f16x4 sh = *(const f16x4*)&s3_s[(n * 16 + l16) * (DIM + 4) + d0];
          #pragma unroll
          for (int r = 0; r < 4; ++r) {
            const float y0 = yv[n][r];
            const float s  = (float)sh[r];
            const float tv = acc3[n][r] + ((const float*)&b3v)[r] + y0 * mm4[r];
            const float e  = __builtin_amdgcn_exp2f(s * LOG2E);
            yv[n][r] = mm4[r] * y0 + om[r] * (y0 * e + tv);
            lda[n]  += om[r] * s;
          }
        }
      }
    } // net
  } // layers

  // y out: coalesced dwordx4 per n
  #pragma unroll
  for (int n = 0; n < 4; ++n) {
    float4 v; v.x = yv[n][0]; v.y = yv[n][1]; v.z = yv[n][2]; v.w = yv[n][3];
    *(float4*)&y_out[(size_t)(row0 + n * 16 + l16) * DIM + d0] = v;
  }

  // logdet: lda[n] holds this lane's D-slice sum; reduce over quad (shfl),
  // then over waves (LDS, aliased on xm_s).
  float v0 = lda[0], v1 = lda[1], v2 = lda[2], v3 = lda[3];
  v0 += __shfl_xor(v0, 16); v0 += __shfl_xor(v0, 32);
  v1 += __shfl_xor(v1, 16); v1 += __shfl_xor(v1, 32);
  v2 += __shfl_xor(v2, 16); v2 += __shfl_xor(v2, 32);
  v3 += __shfl_xor(v3, 16); v3 += __shfl_xor(v3, 32);
  __syncthreads();                   // xm region now safe to reuse
  if (quad == 0) {
    ld_red[(0 * 16 + l16) * 4 + wv] = v0;
    ld_red[(1 * 16 + l16) * 4 + wv] = v1;
    ld_red[(2 * 16 + l16) * 4 + wv] = v2;
    ld_red[(3 * 16 + l16) * 4 + wv] = v3;
  }
  __syncthreads();
  if (tid < BM)
    ld_out[row0 + tid] = ld_red[tid * 4 + 0] + ld_red[tid * 4 + 1]
                       + ld_red[tid * 4 + 2] + ld_red[tid * 4 + 3];
}

extern "C" void kernel_launch(void* const* d_in, const int* in_sizes, int n_in,
                              void* d_out, int out_size, void* d_ws, size_t ws_size,
                              hipStream_t stream) {
  const float* x     = (const float*)d_in[0];
  const float* masks = (const float*)d_in[1];
  const float* sW1f  = (const float*)d_in[2];
  const float* sb1   = (const float*)d_in[3];
  const float* sW2f  = (const float*)d_in[4];
  const float* sb2   = (const float*)d_in[5];
  const float* sW3f  = (const float*)d_in[6];
  const float* sb3   = (const float*)d_in[7];
  const float* scl   = (const float*)d_in[8];
  const float* tW1f  = (const float*)d_in[9];
  const float* tb1   = (const float*)d_in[10];
  const float* tW2f  = (const float*)d_in[11];
  const float* tb2   = (const float*)d_in[12];
  const float* tW3f  = (const float*)d_in[13];
  const float* tb3   = (const float*)d_in[14];
  (void)in_sizes; (void)n_in; (void)out_size; (void)ws_size;

  const int W1SZ = NLAYER * HID * DIM;   // 131072
  const int W2SZ = NLAYER * HID * HID;   // 524288
  const int W3SZ = NLAYER * DIM * HID;   // 131072
  f16* wS1 = (f16*)d_ws;
  f16* wS2 = wS1 + W1SZ;
  f16* wS3 = wS2 + W2SZ;
  f16* wT1 = wS3 + W3SZ;
  f16* wT2 = wT1 + W1SZ;
  f16* wT3 = wT2 + W2SZ;

  // total float4 quads = 393216 -> 1536 blocks x 256
  cvt6_kernel<<<1536, 256, 0, stream>>>(sW1f, wS1, sW2f, wS2, sW3f, wS3,
                                        tW1f, wT1, tW2f, wT2, tW3f, wT3);

  float* y_out  = (float*)d_out;
  float* ld_out = y_out + (size_t)BATCH * DIM;
  flow_kernel<<<BATCH / BM, NTHREADS, 0, stream>>>(
      x, masks, wS1, wS2, wS3, sb1, sb2, sb3, scl,
      wT1, wT2, wT3, tb1, tb2, tb3, y_out, ld_out);
}

// Round 8
// 952.981 us; speedup vs baseline: 1.7842x; 1.0430x over previous
//
#include <hip/hip_runtime.h>

// RealNVP forward, fused across all 8 coupling layers.  Round 8.
// B=131072, D=64, H=256, L=8. out = y[B*D] ++ logdet[B], fp32.
//
// R7 -> R8: drop the XOR swizzle, return to R2-style PADDED LINEAR LDS.
// Evidence: (a) swizzle gave MORE bank conflicts than the pad (6.0e7 vs
// R2's 3.8e7); (b) swizzled offsets depend on k, so every (n,kt) LDS access
// needs a computed address register -> ~16 live addr temps = the ~8-reg
// overflow that kept scratch spill alive through R4-R7 (WRITE 306 MB vs 34
// ideal); with linear rows, ds_read/global_load IMMEDIATE offsets absorb
// kt*64, leaving 4 address regs per K-loop. Strides (halfs): act 264,
// xm 72, s3 68 -- rows 16B-aligned, stride = 4 banks mod 32 -> 2-way alias
// (free, m136). LDS 33792+9216+8704 = 51712 B -> 3 blocks/CU at (256,3).
// Everything else = R7: transposed matmuls (C reg-index runs along the
// contiguous dim), s3 state in LDS, v_cvt_pkrtz packing, fp16 weights in ws.

#define BATCH    131072
#define DIM      64
#define HID      256
#define NLAYER   8
#define BM       64
#define NTHREADS 256

#define ACT_S 264   // act row stride, halfs (256 + 8)
#define XM_S  72    // xm  row stride, halfs (64 + 8)
#define S3_S  68    // s3  row stride, halfs (64 + 4)

typedef _Float16 f16;
typedef __attribute__((ext_vector_type(8))) _Float16 f16x8;
typedef __attribute__((ext_vector_type(4))) _Float16 f16x4;
typedef __attribute__((ext_vector_type(2))) _Float16 f16x2;
typedef __attribute__((ext_vector_type(4))) float    f32x4;

#define TWO_LOG2E 2.8853900817779268f   // 2*log2(e)
#define LOG2E     1.4426950408889634f

__device__ __forceinline__ float tanh_fast(float x) {
  // tanh(x) = 1 - 2/(e^{2x}+1); exact +-1 limits at inf -> no clamps needed.
  float e = __builtin_amdgcn_exp2f(x * TWO_LOG2E);
  return 1.f - 2.f * __builtin_amdgcn_rcpf(e + 1.f);
}

// Pack 4 f32 -> f16x4 with two v_cvt_pkrtz_f16_f32.
__device__ __forceinline__ f16x4 pk4(float a, float b, float c, float d) {
  f16x2 lo = __builtin_bit_cast(f16x2, __builtin_amdgcn_cvt_pkrtz(a, b));
  f16x2 hi = __builtin_bit_cast(f16x2, __builtin_amdgcn_cvt_pkrtz(c, d));
  f16x4 o; o[0] = lo[0]; o[1] = lo[1]; o[2] = hi[0]; o[3] = hi[1];
  return o;
}

// fp32 -> fp16 weight pack, all 6 tensors in one launch.
__global__ void cvt6_kernel(const float* s0, f16* d0, const float* s1, f16* d1,
                            const float* s2, f16* d2, const float* s3, f16* d3,
                            const float* s4, f16* d4, const float* s5, f16* d5) {
  // quad counts: 32768, 131072, 32768, 32768, 131072, 32768 (total 393216)
  int i = blockIdx.x * blockDim.x + threadIdx.x;
  const float* s; f16* d; int base;
  if      (i < 32768)  { s = s0; d = d0; base = 0; }
  else if (i < 163840) { s = s1; d = d1; base = 32768; }
  else if (i < 196608) { s = s2; d = d2; base = 163840; }
  else if (i < 229376) { s = s3; d = d3; base = 196608; }
  else if (i < 360448) { s = s4; d = d4; base = 229376; }
  else                 { s = s5; d = d5; base = 360448; }
  int k = i - base;
  float4 v = ((const float4*)s)[k];
  ((f16x4*)d)[k] = pk4(v.x, v.y, v.z, v.w);
}

__global__ __launch_bounds__(NTHREADS, 3) void flow_kernel(
    const float* __restrict__ x, const float* __restrict__ masks,
    const f16* __restrict__ wS1, const f16* __restrict__ wS2, const f16* __restrict__ wS3,
    const float* __restrict__ sb1, const float* __restrict__ sb2, const float* __restrict__ sb3,
    const float* __restrict__ scl,
    const f16* __restrict__ wT1, const f16* __restrict__ wT2, const f16* __restrict__ wT3,
    const float* __restrict__ tb1, const float* __restrict__ tb2, const float* __restrict__ tb3,
    float* __restrict__ y_out, float* __restrict__ ld_out)
{
  __shared__ __attribute__((aligned(16))) f16 act [BM * ACT_S];   // 33792 B
  __shared__ __attribute__((aligned(16))) f16 xm_s[BM * XM_S];    //  9216 B
  __shared__ __attribute__((aligned(16))) f16 s3_s[BM * S3_S];    //  8704 B
  float* ld_red = (float*)xm_s;  // aliased: xm dead by the time logdet reduces

  const int tid  = threadIdx.x;
  const int lane = tid & 63;
  const int wv   = tid >> 6;        // wave 0..3: hidden-quarter (mm1/mm2), D-quarter (mm3)
  const int quad = lane >> 4;
  const int l16  = lane & 15;
  const int row0 = blockIdx.x * BM;
  const int d0   = wv * 16 + quad * 4;   // this lane's D base (4 consecutive)

  // Per-lane state: batch row = n*16+l16, D = d0+r  (mm3 C-layout).
  float yv[4][4];    // flow state, fp32
  float lda[4];      // logdet accumulator per n
  #pragma unroll
  for (int n = 0; n < 4; ++n) {
    const float4 v = *(const float4*)&x[(size_t)(row0 + n * 16 + l16) * DIM + d0];
    yv[n][0] = v.x; yv[n][1] = v.y; yv[n][2] = v.z; yv[n][3] = v.w;
    lda[n] = 0.f;
  }

  const f32x4 fzero = {0.f, 0.f, 0.f, 0.f};

  #pragma unroll 1
  for (int l = 0; l < NLAYER; ++l) {
    const float4 mv = *(const float4*)&masks[l * DIM + d0];   // mask for D=d0..d0+3

    // xm = y*mask -> LDS (B-operand of mm1), one b64 per n
    #pragma unroll
    for (int n = 0; n < 4; ++n)
      *(f16x4*)&xm_s[(n * 16 + l16) * XM_S + d0] =
          pk4(yv[n][0] * mv.x, yv[n][1] * mv.y, yv[n][2] * mv.z, yv[n][3] * mv.w);
    __syncthreads();                                     // (1) xm ready

    #pragma unroll 1
    for (int net = 0; net < 2; ++net) {
      const f16*   W1 = (net ? wT1 : wS1) + l * HID * DIM;
      const f16*   W2 = (net ? wT2 : wS2) + l * HID * HID;
      const f16*   W3 = (net ? wT3 : wS3) + l * DIM * HID;
      const float* b1 = (net ? tb1 : sb1) + l * HID;
      const float* b2 = (net ? tb2 : sb2) + l * HID;
      const float* b3 = (net ? tb3 : sb3) + l * DIM;

      f32x4 acc[4][4];   // [m = hidden tile][n = batch tile]
      #pragma unroll
      for (int m = 0; m < 4; ++m)
        #pragma unroll
        for (int n = 0; n < 4; ++n) acc[m][n] = fzero;

      // ---- mm1 (transposed): C[h, b] = W1 @ xm^T ----
      // Fixed row bases; kt offsets fold into load immediates.
      #pragma unroll
      for (int kt = 0; kt < 2; ++kt) {
        const int k0 = kt * 32 + quad * 8;
        f16x8 afr[4];
        #pragma unroll
        for (int m = 0; m < 4; ++m)
          afr[m] = *(const f16x8*)&W1[(wv * 64 + m * 16 + l16) * DIM + k0];
        #pragma unroll
        for (int n = 0; n < 4; ++n) {
          const f16x8 bfr = *(const f16x8*)&xm_s[(n * 16 + l16) * XM_S + k0];
          #pragma unroll
          for (int m = 0; m < 4; ++m)
            acc[m][n] = __builtin_amdgcn_mfma_f32_16x16x32_f16(afr[m], bfr, acc[m][n], 0, 0, 0);
        }
      }
      // ep1: act[b, h..h+3] = tanh(. + b1)  -- contiguous b64 per (m,n)
      #pragma unroll
      for (int m = 0; m < 4; ++m) {
        const int   h0  = wv * 64 + m * 16 + quad * 4;
        const float4 bv = *(const float4*)&b1[h0];
        #pragma unroll
        for (int n = 0; n < 4; ++n)
          *(f16x4*)&act[(n * 16 + l16) * ACT_S + h0] =
              pk4(tanh_fast(acc[m][n][0] + bv.x), tanh_fast(acc[m][n][1] + bv.y),
                  tanh_fast(acc[m][n][2] + bv.z), tanh_fast(acc[m][n][3] + bv.w));
      }
      __syncthreads();                                   // (2) h1 ready

      // ---- mm2 (transposed): W2 @ h1^T, residual tanh ----
      #pragma unroll
      for (int m = 0; m < 4; ++m)
        #pragma unroll
        for (int n = 0; n < 4; ++n) acc[m][n] = fzero;
      #pragma unroll 2
      for (int kt = 0; kt < 8; ++kt) {
        const int k0 = kt * 32 + quad * 8;
        f16x8 afr[4];
        #pragma unroll
        for (int m = 0; m < 4; ++m)
          afr[m] = *(const f16x8*)&W2[(wv * 64 + m * 16 + l16) * HID + k0];
        #pragma unroll
        for (int n = 0; n < 4; ++n) {
          const f16x8 bfr = *(const f16x8*)&act[(n * 16 + l16) * ACT_S + k0];
          #pragma unroll
          for (int m = 0; m < 4; ++m)
            acc[m][n] = __builtin_amdgcn_mfma_f32_16x16x32_f16(afr[m], bfr, acc[m][n], 0, 0, 0);
        }
      }
      __syncthreads();                                   // (3) all done reading act
      #pragma unroll
      for (int m = 0; m < 4; ++m) {
        const int   h0  = wv * 64 + m * 16 + quad * 4;
        const float4 bv = *(const float4*)&b2[h0];
        #pragma unroll
        for (int n = 0; n < 4; ++n) {
          f16x4* p = (f16x4*)&act[(n * 16 + l16) * ACT_S + h0];
          const f16x4 prev = *p;                         // own cell (same lane wrote it)
          *p = pk4(tanh_fast(acc[m][n][0] + bv.x + (float)prev[0]),
                   tanh_fast(acc[m][n][1] + bv.y + (float)prev[1]),
                   tanh_fast(acc[m][n][2] + bv.z + (float)prev[2]),
                   tanh_fast(acc[m][n][3] + bv.w + (float)prev[3]));
        }
      }
      __syncthreads();                                   // (4) h2 ready

      // ---- mm3 (transposed): W3 @ h2^T -> C[D, b] ----
      f32x4 acc3[4];
      #pragma unroll
      for (int n = 0; n < 4; ++n) acc3[n] = fzero;
      #pragma unroll 2
      for (int kt = 0; kt < 8; ++kt) {
        const int k0  = kt * 32 + quad * 8;
        const f16x8 a3 = *(const f16x8*)&W3[(wv * 16 + l16) * HID + k0];
        #pragma unroll
        for (int n = 0; n < 4; ++n) {
          const f16x8 bfr = *(const f16x8*)&act[(n * 16 + l16) * ACT_S + k0];
          acc3[n] = __builtin_amdgcn_mfma_f32_16x16x32_f16(a3, bfr, acc3[n], 0, 0, 0);
        }
      }
      if (net == 0) __syncthreads();   // (5) act free for net1's ep1
      // net1's post-mm3 overwrite of act is guarded by next layer's barrier (1)

      const float4 b3v = *(const float4*)&b3[d0];
      if (net == 0) {
        const float4 sv = *(const float4*)&scl[l * DIM + d0];
        // s3 -> LDS (same lane reads it back in net1's epilogue; no barrier
        // needed for same-lane LDS RAW).
        #pragma unroll
        for (int n = 0; n < 4; ++n)
          *(f16x4*)&s3_s[(n * 16 + l16) * S3_S + d0] =
              pk4((tanh_fast(acc3[n][0] + b3v.x) + yv[n][0] * mv.x) * sv.x,
                  (tanh_fast(acc3[n][1] + b3v.y) + yv[n][1] * mv.y) * sv.y,
                  (tanh_fast(acc3[n][2] + b3v.z) + yv[n][2] * mv.z) * sv.z,
                  (tanh_fast(acc3[n][3] + b3v.w) + yv[n][3] * mv.w) * sv.w);
      } else {
        const float om[4] = {1.f - mv.x, 1.f - mv.y, 1.f - mv.z, 1.f - mv.w};
        const float mm4[4] = {mv.x, mv.y, mv.z, mv.w};
        #pragma unroll
        for (int n = 0; n < 4; ++n) {
          const f16x4 sh = *(const f16x4*)&s3_s[(n * 16 + l16) * S3_S + d0];
          #pragma unroll
          for (int r = 0; r < 4; ++r) {
            const float y0 = yv[n][r];
            const float s  = (float)sh[r];
            const float tv = acc3[n][r] + ((const float*)&b3v)[r] + y0 * mm4[r];
            const float e  = __builtin_amdgcn_exp2f(s * LOG2E);
            yv[n][r] = mm4[r] * y0 + om[r] * (y0 * e + tv);
            lda[n]  += om[r] * s;
          }
        }
      }
    } // net
  } // layers

  // y out: coalesced dwordx4 per n
  #pragma unroll
  for (int n = 0; n < 4; ++n) {
    float4 v; v.x = yv[n][0]; v.y = yv[n][1]; v.z = yv[n][2]; v.w = yv[n][3];
    *(float4*)&y_out[(size_t)(row0 + n * 16 + l16) * DIM + d0] = v;
  }

  // logdet: lda[n] holds this lane's D-slice sum; reduce over quad (shfl),
  // then over waves (LDS, aliased on xm_s).
  float v0 = lda[0], v1 = lda[1], v2 = lda[2], v3 = lda[3];
  v0 += __shfl_xor(v0, 16); v0 += __shfl_xor(v0, 32);
  v1 += __shfl_xor(v1, 16); v1 += __shfl_xor(v1, 32);
  v2 += __shfl_xor(v2, 16); v2 += __shfl_xor(v2, 32);
  v3 += __shfl_xor(v3, 16); v3 += __shfl_xor(v3, 32);
  __syncthreads();                   // xm region now safe to reuse
  if (quad == 0) {
    ld_red[(0 * 16 + l16) * 4 + wv] = v0;
    ld_red[(1 * 16 + l16) * 4 + wv] = v1;
    ld_red[(2 * 16 + l16) * 4 + wv] = v2;
    ld_red[(3 * 16 + l16) * 4 + wv] = v3;
  }
  __syncthreads();
  if (tid < BM)
    ld_out[row0 + tid] = ld_red[tid * 4 + 0] + ld_red[tid * 4 + 1]
                       + ld_red[tid * 4 + 2] + ld_red[tid * 4 + 3];
}

extern "C" void kernel_launch(void* const* d_in, const int* in_sizes, int n_in,
                              void* d_out, int out_size, void* d_ws, size_t ws_size,
                              hipStream_t stream) {
  const float* x     = (const float*)d_in[0];
  const float* masks = (const float*)d_in[1];
  const float* sW1f  = (const float*)d_in[2];
  const float* sb1   = (const float*)d_in[3];
  const float* sW2f  = (const float*)d_in[4];
  const float* sb2   = (const float*)d_in[5];
  const float* sW3f  = (const float*)d_in[6];
  const float* sb3   = (const float*)d_in[7];
  const float* scl   = (const float*)d_in[8];
  const float* tW1f  = (const float*)d_in[9];
  const float* tb1   = (const float*)d_in[10];
  const float* tW2f  = (const float*)d_in[11];
  const float* tb2   = (const float*)d_in[12];
  const float* tW3f  = (const float*)d_in[13];
  const float* tb3   = (const float*)d_in[14];
  (void)in_sizes; (void)n_in; (void)out_size; (void)ws_size;

  const int W1SZ = NLAYER * HID * DIM;   // 131072
  const int W2SZ = NLAYER * HID * HID;   // 524288
  const int W3SZ = NLAYER * DIM * HID;   // 131072
  f16* wS1 = (f16*)d_ws;
  f16* wS2 = wS1 + W1SZ;
  f16* wS3 = wS2 + W2SZ;
  f16* wT1 = wS3 + W3SZ;
  f16* wT2 = wT1 + W1SZ;
  f16* wT3 = wT2 + W2SZ;

  // total float4 quads = 393216 -> 1536 blocks x 256
  cvt6_kernel<<<1536, 256, 0, stream>>>(sW1f, wS1, sW2f, wS2, sW3f, wS3,
                                        tW1f, wT1, tW2f, wT2, tW3f, wT3);

  float* y_out  = (float*)d_out;
  float* ld_out = y_out + (size_t)BATCH * DIM;
  flow_kernel<<<BATCH / BM, NTHREADS, 0, stream>>>(
      x, masks, wS1, wS2, wS3, sb1, sb2, sb3, scl,
      wT1, wT2, wT3, tb1, tb2, tb3, y_out, ld_out);
}